// Round 1
// baseline (664.575 us; speedup 1.0000x reference)
//
#include <hip/hip_runtime.h>

#define TT 36
#define DD 64
#define NNODES 207
#define BB 16
#define NH 8
#define DPH 8
#define LN_EPS 1e-5f

__global__ __launch_bounds__(256) void fused_attn_kernel(
    const float* __restrict__ X, const float* __restrict__ Qg,
    const float* __restrict__ Kg, const float* __restrict__ Vg,
    const float* __restrict__ Wv, const float* __restrict__ bv,
    const float* __restrict__ Wo, const float* __restrict__ bo,
    const float* __restrict__ cqw, const float* __restrict__ cqb,
    const float* __restrict__ ckw, const float* __restrict__ ckb,
    const float* __restrict__ gam, const float* __restrict__ bet,
    float* __restrict__ out)
{
    // LDS: 73,824 B total
    __shared__ float Qs[TT][DD];      // raw Q rows for this (b,n)
    __shared__ float Ks[TT][DD];
    __shared__ float Vr[TT][DD];      // raw V
    __shared__ float Vh[TT][68];      // projected V (pad 68 for float4-friendly, conflict-free)
    __shared__ float Ctx[TT][68];     // per-head context accum (disjoint cols per head)
    __shared__ float Qh[TT][68];      // current-head conv outputs
    __shared__ float Kh[TT][68];
    __shared__ float P[TT][38];       // scores/probs; col 36 holds row sum
    __shared__ float bv_s[DD], bo_s[DD], bq_s[DD], bk_s[DD], g_s[DD], be_s[DD];

    const int tid  = threadIdx.x;
    const int lane = tid & 63;
    const int wave = tid >> 6;
    const int blk  = blockIdx.x;
    const int b    = blk / NNODES;
    const int n    = blk - b * NNODES;

    // ---- stage Q/K/V tiles + bias vectors ----
    for (int idx = tid; idx < TT * DD; idx += 256) {
        int t = idx >> 6, o = idx & 63;
        int g = ((b * TT + t) * NNODES + n) * DD + o;
        Qs[t][o] = Qg[g];
        Ks[t][o] = Kg[g];
        Vr[t][o] = Vg[g];
    }
    if (tid < DD) {
        bv_s[tid] = bv[tid];  bo_s[tid] = bo[tid];
        bq_s[tid] = cqb[tid]; bk_s[tid] = ckb[tid];
        g_s[tid]  = gam[tid]; be_s[tid] = bet[tid];
    }
    __syncthreads();

    // ---- phase 1: Vh = Vr @ Wv^T + bv  (lane = output col o, wave-strided t) ----
    {
        float4 wrow[16];
        #pragma unroll
        for (int j = 0; j < 16; ++j)
            wrow[j] = reinterpret_cast<const float4*>(Wv + lane * DD)[j];
        for (int t = wave; t < TT; t += 4) {
            float acc = bv_s[lane];
            const float4* vr = reinterpret_cast<const float4*>(&Vr[t][0]);
            #pragma unroll
            for (int j = 0; j < 16; ++j) {
                float4 v = vr[j];
                acc += v.x*wrow[j].x + v.y*wrow[j].y + v.z*wrow[j].z + v.w*wrow[j].w;
            }
            Vh[t][lane] = acc;
        }
    }

    // conv weights into registers: lane holds output-channel c = lane
    // layout: w[c][i][kt] at c*24 + i*3 + kt
    float wq_r[24], wk_r[24];
    #pragma unroll
    for (int j = 0; j < 6; ++j) {
        float4 a = reinterpret_cast<const float4*>(cqw + lane * 24)[j];
        wq_r[4*j] = a.x; wq_r[4*j+1] = a.y; wq_r[4*j+2] = a.z; wq_r[4*j+3] = a.w;
        float4 c = reinterpret_cast<const float4*>(ckw + lane * 24)[j];
        wk_r[4*j] = c.x; wk_r[4*j+1] = c.y; wk_r[4*j+2] = c.z; wk_r[4*j+3] = c.w;
    }
    __syncthreads();   // Vh, staging all ready

    // ---- per-head: causal conv -> scores -> softmax -> ctx ----
    for (int h = 0; h < NH; ++h) {
        // causal conv (kernel 3, pad-left 2): uses rows t-2, t-1, t
        for (int t = wave; t < TT; t += 4) {
            float aq = bq_s[lane], ak = bk_s[lane];
            #pragma unroll
            for (int kt = 0; kt < 3; ++kt) {
                int t0 = t + kt - 2;
                if (t0 >= 0) {
                    #pragma unroll
                    for (int i = 0; i < 8; ++i) {
                        aq += Qs[t0][h*8 + i] * wq_r[i*3 + kt];
                        ak += Ks[t0][h*8 + i] * wk_r[i*3 + kt];
                    }
                }
            }
            Qh[t][lane] = aq;
            Kh[t][lane] = ak;
        }
        __syncthreads();

        // scores S[q][k] = (Qh[q,:] . Kh[k,:]) / 8   (k>q entries never read)
        for (int idx = tid; idx < TT*TT; idx += 256) {
            int q = idx / TT, k = idx - q*TT;
            const float4* qr = reinterpret_cast<const float4*>(&Qh[q][0]);
            const float4* kr = reinterpret_cast<const float4*>(&Kh[k][0]);
            float acc = 0.f;
            #pragma unroll
            for (int j = 0; j < 16; ++j) {
                float4 a = qr[j], c = kr[j];
                acc += a.x*c.x + a.y*c.y + a.z*c.z + a.w*c.w;
            }
            P[q][k] = acc * 0.125f;
        }
        __syncthreads();

        // softmax over k<=q, 2 threads per row
        if (tid < 2*TT) {
            int q = tid >> 1, hf = tid & 1;
            float m = -3.4e38f;
            for (int k = hf; k <= q; k += 2) m = fmaxf(m, P[q][k]);
            m = fmaxf(m, __shfl_xor(m, 1));
            float s = 0.f;
            for (int k = hf; k <= q; k += 2) {
                float e = __expf(P[q][k] - m);
                P[q][k] = e;
                s += e;
            }
            s += __shfl_xor(s, 1);
            if (hf == 0) P[q][36] = s;
        }
        __syncthreads();

        // ctx[q][h*8+e] = sum_{k<=q} P[q][k] * Vh[k][h*8+e] / rowsum
        for (int idx = tid; idx < TT*DPH; idx += 256) {
            int q = idx >> 3, e = idx & 7;
            float acc = 0.f;
            for (int k = 0; k <= q; ++k) acc += P[q][k] * Vh[k][h*8 + e];
            Ctx[q][h*8 + e] = acc / P[q][36];
        }
        __syncthreads();
    }

    // ---- final: out = Ctx @ Wo^T + bo + X, then LayerNorm over d ----
    {
        float4 wrow[16];
        #pragma unroll
        for (int j = 0; j < 16; ++j)
            wrow[j] = reinterpret_cast<const float4*>(Wo + lane * DD)[j];
        for (int t = wave; t < TT; t += 4) {
            float acc = bo_s[lane];
            const float4* cr = reinterpret_cast<const float4*>(&Ctx[t][0]);
            #pragma unroll
            for (int j = 0; j < 16; ++j) {
                float4 v = cr[j];
                acc += v.x*wrow[j].x + v.y*wrow[j].y + v.z*wrow[j].z + v.w*wrow[j].w;
            }
            int g = ((b * TT + t) * NNODES + n) * DD + lane;
            acc += X[g];
            float s1 = acc, s2 = acc * acc;
            #pragma unroll
            for (int off = 32; off > 0; off >>= 1) {
                s1 += __shfl_xor(s1, off);
                s2 += __shfl_xor(s2, off);
            }
            float mu  = s1 * (1.f/64.f);
            float var = s2 * (1.f/64.f) - mu * mu;
            out[g] = (acc - mu) * rsqrtf(var + LN_EPS) * g_s[lane] + be_s[lane];
        }
    }
}

extern "C" void kernel_launch(void* const* d_in, const int* in_sizes, int n_in,
                              void* d_out, int out_size, void* d_ws, size_t ws_size,
                              hipStream_t stream) {
    const float* X   = (const float*)d_in[0];
    const float* Q   = (const float*)d_in[1];
    const float* K   = (const float*)d_in[2];
    const float* V   = (const float*)d_in[3];
    const float* Wv  = (const float*)d_in[4];
    const float* bv  = (const float*)d_in[5];
    const float* Wo  = (const float*)d_in[6];
    const float* bo  = (const float*)d_in[7];
    const float* cqw = (const float*)d_in[8];
    const float* cqb = (const float*)d_in[9];
    const float* ckw = (const float*)d_in[10];
    const float* ckb = (const float*)d_in[11];
    const float* gam = (const float*)d_in[12];
    const float* bet = (const float*)d_in[13];
    float* out = (float*)d_out;

    dim3 grid(BB * NNODES), block(256);
    hipLaunchKernelGGL(fused_attn_kernel, grid, block, 0, stream,
                       X, Q, K, V, Wv, bv, Wo, bo, cqw, cqb, ckw, ckb, gam, bet, out);
}

// Round 2
// 318.282 us; speedup vs baseline: 2.0880x; 2.0880x over previous
//
#include <hip/hip_runtime.h>
#include <hip/hip_bf16.h>

#define TT 36
#define DD 64
#define NN 207
#define BBATCH 16
#define NH 8
#define LN_EPS 1e-5f

__global__ __launch_bounds__(512, 4) void fused_attn2(
    const float* __restrict__ X, const float* __restrict__ Qg,
    const float* __restrict__ Kg, const float* __restrict__ Vg,
    const float* __restrict__ Wv, const float* __restrict__ bv,
    const float* __restrict__ Wo, const float* __restrict__ bo,
    const float* __restrict__ cqw, const float* __restrict__ cqb_g,
    const float* __restrict__ ckw,
    const float* __restrict__ gam, const float* __restrict__ bet,
    float* __restrict__ out)
{
    __shared__ float Qs[TT][68];
    __shared__ float Ks[TT][68];
    __shared__ float Vh[TT][68];
    __shared__ float VrCtx[TT][68];      // raw V, later ctx
    __shared__ float M_s[25][28];        // rows 0..23: 0.125*Wq^T Wk ; row 24: 0.125*Wk^T cqb
    __shared__ __align__(16) unsigned char Ubuf[23040]; // Wq/Wk staging, later P (bf16 [8][36][40])
    __shared__ float bv_s[64], bo_s[64], g_s[64], be_s[64], cqb_s[64];

    float* Wq_s = (float*)Ubuf;          // [64][24]
    float* Wk_s = Wq_s + 64 * 24;
    __hip_bfloat16* P_s = (__hip_bfloat16*)Ubuf;

    const int tid  = threadIdx.x;
    const int lane = tid & 63;
    const int wave = tid >> 6;
    const int b    = blockIdx.x / NN;
    const int n    = blockIdx.x % NN;

    // ---- staging ----
    const float4* Q4 = (const float4*)(Qg + (size_t)(b * TT * NN + n) * DD);
    const float4* K4 = (const float4*)(Kg + (size_t)(b * TT * NN + n) * DD);
    const float4* V4 = (const float4*)(Vg + (size_t)(b * TT * NN + n) * DD);
    for (int idx = tid; idx < TT * 16; idx += 512) {
        int t = idx >> 4, o = idx & 15;
        ((float4*)&Qs[t][0])[o]    = Q4[t * 3312 + o];
        ((float4*)&Ks[t][0])[o]    = K4[t * 3312 + o];
        ((float4*)&VrCtx[t][0])[o] = V4[t * 3312 + o];
    }
    for (int idx = tid; idx < 768; idx += 512) {
        if (idx < 384) ((float4*)Wq_s)[idx]       = ((const float4*)cqw)[idx];
        else           ((float4*)Wk_s)[idx - 384] = ((const float4*)ckw)[idx - 384];
    }
    if (tid < 64) {
        bv_s[tid] = bv[tid]; bo_s[tid] = bo[tid];
        g_s[tid] = gam[tid]; be_s[tid] = bet[tid];
        cqb_s[tid] = cqb_g[tid];
    }
    __syncthreads();

    // ---- M = 0.125 * Wq^T Wk (row 24: 0.125 * Wk^T cqb) ----
    for (int u = tid; u < 600; u += 512) {
        int j = u / 24, j2 = u - j * 24;
        float acc = 0.f;
        if (j < 24) {
            for (int c = 0; c < 64; ++c) acc += Wq_s[c * 24 + j] * Wk_s[c * 24 + j2];
        } else {
            for (int c = 0; c < 64; ++c) acc += cqb_s[c] * Wk_s[c * 24 + j2];
        }
        M_s[j][j2] = acc * 0.125f;
    }

    // ---- Vh = Vr @ Wv^T + bv (lane = out col, waves stride t) ----
    {
        float4 wrow[16];
        const float4* wr = (const float4*)(Wv + lane * DD);
        #pragma unroll
        for (int j = 0; j < 16; ++j) wrow[j] = wr[j];
        for (int t = wave; t < TT; t += 8) {
            float acc = bv_s[lane];
            const float4* vr = (const float4*)&VrCtx[t][0];
            #pragma unroll
            for (int j = 0; j < 16; ++j) {
                float4 v = vr[j];
                acc += v.x * wrow[j].x + v.y * wrow[j].y + v.z * wrow[j].z + v.w * wrow[j].w;
            }
            Vh[t][lane] = acc;
        }
    }
    __syncthreads();   // M, Vh ready; Wq/Wk region reusable as P

    // ---- per-wave (wave = head): R in regs -> S rows -> softmax -> P(bf16) ----
    {
        const int h = wave, h8 = h * 8;
        const bool kvalid = lane < TT;
        const int k = kvalid ? lane : lane - TT;

        float akr[3][8];
        #pragma unroll
        for (int kt = 0; kt < 3; ++kt) {
            int row = k + kt - 2;
            if (row >= 0) {
                const float4* s = (const float4*)&Ks[row][h8];
                float4 x0 = s[0], x1 = s[1];
                akr[kt][0] = x0.x; akr[kt][1] = x0.y; akr[kt][2] = x0.z; akr[kt][3] = x0.w;
                akr[kt][4] = x1.x; akr[kt][5] = x1.y; akr[kt][6] = x1.z; akr[kt][7] = x1.w;
            } else {
                #pragma unroll
                for (int i = 0; i < 8; ++i) akr[kt][i] = 0.f;
            }
        }

        float R[25];
        #pragma unroll
        for (int j = 0; j < 25; ++j) {
            const float4* mr = (const float4*)&M_s[j][0];
            float4 m0 = mr[0], m1 = mr[1], m2 = mr[2], m3 = mr[3], m4 = mr[4], m5 = mr[5];
            float m[24] = {m0.x,m0.y,m0.z,m0.w, m1.x,m1.y,m1.z,m1.w, m2.x,m2.y,m2.z,m2.w,
                           m3.x,m3.y,m3.z,m3.w, m4.x,m4.y,m4.z,m4.w, m5.x,m5.y,m5.z,m5.w};
            float acc = 0.f;
            #pragma unroll
            for (int i = 0; i < 8; ++i)
                acc += akr[0][i] * m[i*3] + akr[1][i] * m[i*3+1] + akr[2][i] * m[i*3+2];
            R[j] = acc;
        }

        auto sstep = [&](int q, float (&am2)[8], float (&am1)[8], float (&cur)[8]) {
            const float4* s = (const float4*)&Qs[q][h8];
            float4 x0 = s[0], x1 = s[1];
            cur[0] = x0.x; cur[1] = x0.y; cur[2] = x0.z; cur[3] = x0.w;
            cur[4] = x1.x; cur[5] = x1.y; cur[6] = x1.z; cur[7] = x1.w;
            float sc = R[24];
            #pragma unroll
            for (int i = 0; i < 8; ++i)
                sc += am2[i] * R[i*3] + am1[i] * R[i*3+1] + cur[i] * R[i*3+2];
            bool act = kvalid && (k <= q);
            float m = act ? sc : -3.4e38f;
            #pragma unroll
            for (int off = 32; off; off >>= 1) m = fmaxf(m, __shfl_xor(m, off));
            float e = act ? __expf(sc - m) : 0.f;
            float ssum = e;
            #pragma unroll
            for (int off = 32; off; off >>= 1) ssum += __shfl_xor(ssum, off);
            float p = e * __frcp_rn(ssum);
            if (act) P_s[(h * TT + q) * 40 + k] = __float2bfloat16(p);
        };

        float A0[8], A1[8], A2[8];
        #pragma unroll
        for (int i = 0; i < 8; ++i) { A0[i] = 0.f; A1[i] = 0.f; }
        for (int qb = 0; qb < TT; qb += 3) {
            sstep(qb,     A0, A1, A2);
            sstep(qb + 1, A1, A2, A0);
            sstep(qb + 2, A2, A0, A1);
        }
    }
    __syncthreads();

    // ---- ctx[q][h*8+e] = sum_{k<=q} P[h][q][k] * Vh[k][h*8+e]  (into VrCtx) ----
    for (int id = tid; id < 576; id += 512) {
        int hh = id / 72, r = id - hh * 72, q = r >> 1, eh = r & 1;
        const __hip_bfloat16* prow = P_s + (hh * TT + q) * 40;
        float4 acc = {0.f, 0.f, 0.f, 0.f};
        for (int kk = 0; kk <= q; ++kk) {
            float p = __bfloat162float(prow[kk]);
            float4 v = *(const float4*)&Vh[kk][hh * 8 + eh * 4];
            acc.x += p * v.x; acc.y += p * v.y; acc.z += p * v.z; acc.w += p * v.w;
        }
        *(float4*)&VrCtx[q][hh * 8 + eh * 4] = acc;
    }
    __syncthreads();

    // ---- out = Ctx @ Wo^T + bo + X, LayerNorm ----
    {
        float4 wrow[16];
        const float4* wr = (const float4*)(Wo + lane * DD);
        #pragma unroll
        for (int j = 0; j < 16; ++j) wrow[j] = wr[j];
        for (int t = wave; t < TT; t += 8) {
            float acc = bo_s[lane];
            const float4* cr = (const float4*)&VrCtx[t][0];
            #pragma unroll
            for (int j = 0; j < 16; ++j) {
                float4 v = cr[j];
                acc += v.x * wrow[j].x + v.y * wrow[j].y + v.z * wrow[j].z + v.w * wrow[j].w;
            }
            size_t g = ((size_t)(b * TT + t) * NN + n) * DD + lane;
            acc += X[g];
            float s1 = acc, s2 = acc * acc;
            #pragma unroll
            for (int off = 32; off; off >>= 1) {
                s1 += __shfl_xor(s1, off);
                s2 += __shfl_xor(s2, off);
            }
            float mu  = s1 * (1.f / 64.f);
            float var = s2 * (1.f / 64.f) - mu * mu;
            out[g] = (acc - mu) * rsqrtf(var + LN_EPS) * g_s[lane] + be_s[lane];
        }
    }
}

extern "C" void kernel_launch(void* const* d_in, const int* in_sizes, int n_in,
                              void* d_out, int out_size, void* d_ws, size_t ws_size,
                              hipStream_t stream) {
    const float* X   = (const float*)d_in[0];
    const float* Q   = (const float*)d_in[1];
    const float* K   = (const float*)d_in[2];
    const float* V   = (const float*)d_in[3];
    const float* Wv  = (const float*)d_in[4];
    const float* bv  = (const float*)d_in[5];
    const float* Wo  = (const float*)d_in[6];
    const float* bo  = (const float*)d_in[7];
    const float* cqw = (const float*)d_in[8];
    const float* cqb = (const float*)d_in[9];
    const float* ckw = (const float*)d_in[10];
    // d_in[11] (conv_k_b) cancels in softmax -> unused
    const float* gam = (const float*)d_in[12];
    const float* bet = (const float*)d_in[13];
    float* out = (float*)d_out;

    dim3 grid(BBATCH * NN), block(512);
    hipLaunchKernelGGL(fused_attn2, grid, block, 0, stream,
                       X, Q, K, V, Wv, bv, Wo, bo, cqw, cqb, ckw, gam, bet, out);
}